// Round 2
// baseline (171.449 us; speedup 1.0000x reference)
//
#include <hip/hip_runtime.h>

// Input indices (setup_inputs() dict order):
//  0:x 1:W1 2:b1 3:gn1_g 4:gn1_b 5:W2 6:b2 7:W3 8:b3 9:gn2_g 10:gn2_b
//  11:fc1_W[16384,512] 12:fc1_b[512] 13:fc2_W[512,128] 14:fc2_b[128]
//  15:wc_W[128] 16:wc_b[1] 17:sel_W[128] 18:sel_b[1]
//
// Math: groups==C in both GroupNorms -> per-group var==0 exactly -> gn output
// == beta exactly. The conv front-end is dead; flat[k] = relu(gn2_b[k>>8])
// for every batch row, and the two outputs are two scalars replicated 128x.
//
// Channels with gn2_b[c] <= 0 contribute exactly 0 -> their fc1_W rows are
// never read (~halves the 33.5 MB fc1_W stream).

#define ROWS_PER_BLOCK 64  // 16384 rows / 64 = 256 blocks; one quarter-channel per block

__global__ __launch_bounds__(512) void fused_kernel(
    const float* __restrict__ fc1_W,   // [16384, 512] row-major
    const float* __restrict__ gn2_b,   // [64]
    const float* __restrict__ fc1_b,   // [512]
    const float* __restrict__ fc2_W,   // [512,128] row-major
    const float* __restrict__ fc2_b,   // [128]
    const float* __restrict__ wc_W,    // [128]
    const float* __restrict__ wc_b,    // [1]
    const float* __restrict__ sel_W,   // [128]
    const float* __restrict__ sel_b,   // [1]
    float* __restrict__ out,           // [256]: wc[128] then sel[128]
    float* __restrict__ y1acc,         // [512] pre-zeroed accumulator (ws)
    unsigned int* __restrict__ counter)// [1]  pre-zeroed (ws)
{
    const int j   = threadIdx.x;   // column 0..511
    const int bid = blockIdx.x;    // 0..255

    // channel is constant per block: (bid*64 + r) >> 8 == bid >> 2
    float vc = gn2_b[bid >> 2];
    vc = vc > 0.0f ? vc : 0.0f;

    if (vc != 0.0f) {
        const float* p = fc1_W + (size_t)bid * ROWS_PER_BLOCK * 512 + j;
        float acc = 0.0f;
#pragma unroll
        for (int r = 0; r < ROWS_PER_BLOCK; ++r) {
            acc += p[(size_t)r * 512];
        }
        atomicAdd(&y1acc[j], vc * acc);
    }

    // ---- last-block-does-the-tail ----
    __threadfence();  // make this block's y1acc atomics visible device-wide
    __shared__ unsigned int isLast;
    if (j == 0) {
        unsigned int old = atomicAdd(counter, 1u);
        isLast = (old == 255u) ? 1u : 0u;
    }
    __syncthreads();
    if (!isLast) return;

    __threadfence();  // acquire: all 255 other blocks' atomics now visible

    __shared__ float y1s[512];
    __shared__ float part[512];
    __shared__ float redwc[128];
    __shared__ float redsel[128];
    __shared__ float scal[2];

    // y1 = relu(y1acc + fc1_b); volatile -> bypass any stale caching
    volatile const float* vy = (volatile const float*)y1acc;
    float y1 = vy[j] + fc1_b[j];
    y1s[j] = y1 > 0.0f ? y1 : 0.0f;
    __syncthreads();

    // fc2: 4 threads per output column; column c = j&127, quarter q = j>>7
    const int c = j & 127;
    const int q = j >> 7;
    const int i0 = q * 128;
    float acc2 = 0.0f;
#pragma unroll 8
    for (int i = 0; i < 128; ++i) {
        acc2 += y1s[i0 + i] * fc2_W[(size_t)(i0 + i) * 128 + c];
    }
    part[j] = acc2;
    __syncthreads();

    if (j < 128) {
        float y2 = part[j] + part[128 + j] + part[256 + j] + part[384 + j] + fc2_b[j];
        y2 = y2 > 0.0f ? y2 : 0.0f;
        redwc[j]  = y2 * wc_W[j];
        redsel[j] = y2 * sel_W[j];
    }
    __syncthreads();

    if (j == 0) {
        float s0 = 0.0f, s1 = 0.0f;
        for (int i = 0; i < 128; ++i) { s0 += redwc[i]; s1 += redsel[i]; }
        scal[0] = s0 + wc_b[0];
        scal[1] = s1 + sel_b[0];
    }
    __syncthreads();

    if (j < 128) {
        out[j]       = scal[0];  // wc head, replicated over batch
        out[128 + j] = scal[1];  // sel head, replicated over batch
    }
}

extern "C" void kernel_launch(void* const* d_in, const int* in_sizes, int n_in,
                              void* d_out, int out_size, void* d_ws, size_t ws_size,
                              hipStream_t stream) {
    (void)in_sizes; (void)n_in; (void)out_size; (void)ws_size;

    const float* gn2_b = (const float*)d_in[10];
    const float* fc1_W = (const float*)d_in[11];
    const float* fc1_b = (const float*)d_in[12];
    const float* fc2_W = (const float*)d_in[13];
    const float* fc2_b = (const float*)d_in[14];
    const float* wc_W  = (const float*)d_in[15];
    const float* wc_b  = (const float*)d_in[16];
    const float* sel_W = (const float*)d_in[17];
    const float* sel_b = (const float*)d_in[18];

    float*        y1acc   = (float*)d_ws;                 // 512 floats
    unsigned int* counter = (unsigned int*)((char*)d_ws + 512 * sizeof(float));
    float*        out     = (float*)d_out;                // 256 floats

    // ws is poisoned 0xAA before every launch -> zero accumulator + counter.
    hipMemsetAsync(d_ws, 0, 512 * sizeof(float) + sizeof(unsigned int), stream);

    fused_kernel<<<256, 512, 0, stream>>>(fc1_W, gn2_b, fc1_b, fc2_W, fc2_b,
                                          wc_W, wc_b, sel_W, sel_b,
                                          out, y1acc, counter);
}

// Round 3
// 128.924 us; speedup vs baseline: 1.3298x; 1.3298x over previous
//
#include <hip/hip_runtime.h>

// Input indices (setup_inputs() dict order):
//  0:x 1:W1 2:b1 3:gn1_g 4:gn1_b 5:W2 6:b2 7:W3 8:b3 9:gn2_g 10:gn2_b
//  11:fc1_W[16384,512] 12:fc1_b[512] 13:fc2_W[512,128] 14:fc2_b[128]
//  15:wc_W[128] 16:wc_b[1] 17:sel_W[128] 18:sel_b[1]
//
// Math: groups==C in both GroupNorms -> per-group var==0 exactly -> gn output
// == beta exactly. The conv front-end is dead; flat[k] = relu(gn2_b[k>>8])
// for every batch row, and the two outputs are two scalars replicated 128x.
// Channels with gn2_b[c] <= 0 contribute exactly 0 -> their fc1_W rows are
// never read (~20/64 channels live -> FETCH ~10 MB instead of 33.5 MB).
//
// R2 lesson: grid-wide __threadfence + device atomics cost ~+50 us on this
// 8-XCD part. This version has NO atomics, NO fences, NO memset: stage 1
// writes disjoint partials to ws; the tail recomputes liveness from gn2_b
// and never reads poisoned (dead-block) slots.

#define BLOCKS_PER_CH 8            // 64 ch * 8 = 512 blocks
#define ROWS_PER_BLOCK 32          // 256 rows/ch / 8
#define ROWS_PER_THREAD 16         // 32 rows / 2 h-halves

__global__ __launch_bounds__(256) void fc1_partial_kernel(
    const float* __restrict__ fc1_W,   // [16384, 512] row-major
    const float* __restrict__ gn2_b,   // [64]
    float* __restrict__ part)          // [512 blocks][512] partials (ws)
{
    const int t   = threadIdx.x;       // 0..255
    const int c4  = t & 127;           // float4 column group (128 x 4 = 512 cols)
    const int h   = t >> 7;            // row half 0/1
    const int bid = blockIdx.x;        // 0..511
    const int ch  = bid >> 3;          // channel 0..63
    const int sub = bid & 7;

    float vc = gn2_b[ch];
    vc = vc > 0.0f ? vc : 0.0f;
    if (vc == 0.0f) return;            // block-uniform: whole block exits

    const int row0 = ch * 256 + sub * ROWS_PER_BLOCK + h * ROWS_PER_THREAD;
    const float4* p = (const float4*)fc1_W + (size_t)row0 * 128 + c4;

    float4 acc = make_float4(0.f, 0.f, 0.f, 0.f);
#pragma unroll
    for (int r = 0; r < ROWS_PER_THREAD; ++r) {
        float4 v = p[(size_t)r * 128];
        acc.x += v.x; acc.y += v.y; acc.z += v.z; acc.w += v.w;
    }

    __shared__ float4 s[128];
    if (h == 1) s[c4] = acc;
    __syncthreads();
    if (h == 0) {
        float4 o = s[c4];
        o.x = vc * (o.x + acc.x);
        o.y = vc * (o.y + acc.y);
        o.z = vc * (o.z + acc.z);
        o.w = vc * (o.w + acc.w);
        ((float4*)part)[(size_t)bid * 128 + c4] = o;
    }
}

__global__ __launch_bounds__(512) void tail_kernel(
    const float* __restrict__ part,    // [512][512] partials (ws), dead slots poisoned
    const float* __restrict__ gn2_b,   // [64]
    const float* __restrict__ fc1_b,   // [512]
    const float* __restrict__ fc2_W,   // [512,128] row-major
    const float* __restrict__ fc2_b,   // [128]
    const float* __restrict__ wc_W,    // [128]
    const float* __restrict__ wc_b,    // [1]
    const float* __restrict__ sel_W,   // [128]
    const float* __restrict__ sel_b,   // [1]
    float* __restrict__ out)           // [256]: wc[128] then sel[128]
{
    __shared__ float y1s[512];
    __shared__ float p2[512];
    __shared__ float redwc[128];
    __shared__ float redsel[128];
    __shared__ float scal[2];

    const int j = threadIdx.x;         // 0..511

    // y1[j] = relu( fc1_b[j] + sum over LIVE blocks of part[bid][j] )
    float y1 = fc1_b[j];
    for (int ch = 0; ch < 64; ++ch) {
        if (gn2_b[ch] <= 0.0f) continue;           // wave-uniform branch
        const float* pb = part + (size_t)ch * BLOCKS_PER_CH * 512 + j;
#pragma unroll
        for (int sub = 0; sub < BLOCKS_PER_CH; ++sub)
            y1 += pb[(size_t)sub * 512];           // coalesced across j
    }
    y1s[j] = y1 > 0.0f ? y1 : 0.0f;
    __syncthreads();

    // fc2: 4 threads per output column; column c = j&127, quarter q = j>>7
    const int c = j & 127;
    const int q = j >> 7;
    const int i0 = q * 128;
    float acc2 = 0.0f;
#pragma unroll 8
    for (int i = 0; i < 128; ++i) {
        acc2 += y1s[i0 + i] * fc2_W[(size_t)(i0 + i) * 128 + c];
    }
    p2[j] = acc2;
    __syncthreads();

    if (j < 128) {
        float y2 = p2[j] + p2[128 + j] + p2[256 + j] + p2[384 + j] + fc2_b[j];
        y2 = y2 > 0.0f ? y2 : 0.0f;
        redwc[j]  = y2 * wc_W[j];
        redsel[j] = y2 * sel_W[j];
    }
    __syncthreads();

    if (j == 0) {
        float s0 = 0.0f, s1 = 0.0f;
        for (int i = 0; i < 128; ++i) { s0 += redwc[i]; s1 += redsel[i]; }
        scal[0] = s0 + wc_b[0];
        scal[1] = s1 + sel_b[0];
    }
    __syncthreads();

    if (j < 128) {
        out[j]       = scal[0];  // wc head, replicated over batch
        out[128 + j] = scal[1];  // sel head, replicated over batch
    }
}

extern "C" void kernel_launch(void* const* d_in, const int* in_sizes, int n_in,
                              void* d_out, int out_size, void* d_ws, size_t ws_size,
                              hipStream_t stream) {
    (void)in_sizes; (void)n_in; (void)out_size; (void)ws_size;

    const float* gn2_b = (const float*)d_in[10];
    const float* fc1_W = (const float*)d_in[11];
    const float* fc1_b = (const float*)d_in[12];
    const float* fc2_W = (const float*)d_in[13];
    const float* fc2_b = (const float*)d_in[14];
    const float* wc_W  = (const float*)d_in[15];
    const float* wc_b  = (const float*)d_in[16];
    const float* sel_W = (const float*)d_in[17];
    const float* sel_b = (const float*)d_in[18];

    float* part = (float*)d_ws;    // 512 blocks * 512 floats = 1 MB
    float* out  = (float*)d_out;   // 256 floats

    fc1_partial_kernel<<<512, 256, 0, stream>>>(fc1_W, gn2_b, part);

    tail_kernel<<<1, 512, 0, stream>>>(part, gn2_b, fc1_b, fc2_W, fc2_b,
                                       wc_W, wc_b, sel_W, sel_b, out);
}